// Round 1
// baseline (7424.609 us; speedup 1.0000x reference)
//
#include <hip/hip_runtime.h>
#include <math.h>

// Problem constants (FineGrainLoss): B=96 batch, n1=196 image tokens,
// n2=77 text tokens, d=512.
#define BB 96
#define N1 196
#define N2 77
#define DD 512

// S[bi,bt,q,r] = <img[bi,q,:], txt[bt,r,:]>
// i2t[bi,bt] = mean_q max_r S ; t2i[bt,bi] = mean_r max_q S
// One block per (bi,bt). Thread = q row (clamped; duplicates don't affect
// max and are masked out of the mean). Text operand is wave-uniform ->
// scalar loads; hot loop is v_fmac_f32(vacc, s_txt, v_img).
__global__ __launch_bounds__(256, 2) void sim_kernel(
    const float* __restrict__ img, const float* __restrict__ txt,
    float* __restrict__ i2t, float* __restrict__ t2i)
{
    const int bt  = blockIdx.x;
    const int bi  = blockIdx.y;
    const int tid = threadIdx.x;
    const int wid = tid >> 6;
    const int lane = tid & 63;
    const int q = (tid < N1) ? tid : (N1 - 1);   // clamp: dup rows are benign

    const float* __restrict__ imgRow = img + ((size_t)bi * N1 + q) * DD;
    const float* __restrict__ txtB   = txt + (size_t)bt * N2 * DD;

    float acc[N2];
#pragma unroll
    for (int r = 0; r < N2; ++r) acc[r] = 0.f;

    constexpr int KC = 8;
#pragma unroll 1
    for (int k0 = 0; k0 < DD; k0 += KC) {
        float a[KC];
#pragma unroll
        for (int kk = 0; kk < KC; ++kk) a[kk] = imgRow[k0 + kk];
#pragma unroll
        for (int r = 0; r < N2; ++r) {
#pragma unroll
            for (int kk = 0; kk < KC; ++kk)
                acc[r] = fmaf(a[kk], txtB[r * DD + k0 + kk], acc[r]);
        }
    }

    // ---- row max over r (per thread) ----
    float rowmax = acc[0];
#pragma unroll
    for (int r = 1; r < N2; ++r) rowmax = fmaxf(rowmax, acc[r]);

    __shared__ float s_sum[4];
    __shared__ float s_wmax[4 * N2];
    __shared__ float s_col[N2];

    // ---- i2t: sum of rowmax over valid q ----
    float v = (tid < N1) ? rowmax : 0.f;
    v += __shfl_xor(v, 1);
    v += __shfl_xor(v, 2);
    v += __shfl_xor(v, 4);
    v += __shfl_xor(v, 8);
    v += __shfl_xor(v, 16);
    v += __shfl_xor(v, 32);
    if (lane == 0) s_sum[wid] = v;

    // ---- col max over q: wave shuffle-max per r ----
#pragma unroll
    for (int r = 0; r < N2; ++r) {
        float m = acc[r];
        m = fmaxf(m, __shfl_xor(m, 1));
        m = fmaxf(m, __shfl_xor(m, 2));
        m = fmaxf(m, __shfl_xor(m, 4));
        m = fmaxf(m, __shfl_xor(m, 8));
        m = fmaxf(m, __shfl_xor(m, 16));
        m = fmaxf(m, __shfl_xor(m, 32));
        if (lane == 0) s_wmax[wid * N2 + r] = m;
    }
    __syncthreads();

    if (tid == 0) {
        float s = s_sum[0] + s_sum[1] + s_sum[2] + s_sum[3];
        i2t[bi * BB + bt] = s * (1.f / (float)N1);
    }
    if (tid < N2) {
        float m = s_wmax[tid];
        m = fmaxf(m, s_wmax[N2 + tid]);
        m = fmaxf(m, s_wmax[2 * N2 + tid]);
        m = fmaxf(m, s_wmax[3 * N2 + tid]);
        s_col[tid] = m;
    }
    __syncthreads();
    if (tid == 0) {
        float s = 0.f;
#pragma unroll 1
        for (int r = 0; r < N2; ++r) s += s_col[r];
        t2i[bt * BB + bi] = s * (1.f / (float)N2);
    }
}

// CE with arange labels over both [B,B] logit matrices.
// loss = -(1/192) * sum over 192 rows of (diag - logsumexp(row))
__global__ __launch_bounds__(256) void ce_kernel(
    const float* __restrict__ i2t, const float* __restrict__ t2i,
    float* __restrict__ out)
{
    const int tid = threadIdx.x;
    const int wid = tid >> 6;
    const int lane = tid & 63;

    float contrib = 0.f;
    if (tid < 2 * BB) {
        const float* M = (tid < BB) ? i2t : t2i;
        const int b = (tid < BB) ? tid : tid - BB;
        const float* row = M + b * BB;
        float mx = row[0];
#pragma unroll 1
        for (int c = 1; c < BB; ++c) mx = fmaxf(mx, row[c]);
        float s = 0.f;
#pragma unroll 1
        for (int c = 0; c < BB; ++c) s += expf(row[c] - mx);
        float lse = mx + logf(s);
        contrib = row[b] - lse;
    }
    contrib += __shfl_xor(contrib, 1);
    contrib += __shfl_xor(contrib, 2);
    contrib += __shfl_xor(contrib, 4);
    contrib += __shfl_xor(contrib, 8);
    contrib += __shfl_xor(contrib, 16);
    contrib += __shfl_xor(contrib, 32);

    __shared__ float s_part[4];
    if (lane == 0) s_part[wid] = contrib;
    __syncthreads();
    if (tid == 0) {
        float total = s_part[0] + s_part[1] + s_part[2] + s_part[3];
        out[0] = -total * (1.f / (float)(2 * BB));
    }
}

extern "C" void kernel_launch(void* const* d_in, const int* in_sizes, int n_in,
                              void* d_out, int out_size, void* d_ws, size_t ws_size,
                              hipStream_t stream) {
    const float* img = (const float*)d_in[0];   // [96,196,512] fp32
    const float* txt = (const float*)d_in[1];   // [96,77,512] fp32
    float* i2t = (float*)d_ws;                  // [96,96]
    float* t2i = i2t + BB * BB;                 // [96,96]  (73.7 KB total << ws)

    dim3 grid(BB, BB);
    sim_kernel<<<grid, 256, 0, stream>>>(img, txt, i2t, t2i);
    ce_kernel<<<1, 256, 0, stream>>>(i2t, t2i, (float*)d_out);
}

// Round 2
// 681.424 us; speedup vs baseline: 10.8957x; 10.8957x over previous
//
#include <hip/hip_runtime.h>
#include <math.h>

// FineGrainLoss: B=96, n1=196 (image tokens), n2=77 (text tokens), d=512.
#define BB 96
#define N1 196
#define N2 77
#define DD 512

#define MT 13   // M tiles of 16 (208 rows, 196 valid)
#define NT 5    // N tiles of 16 (80 cols, 77 valid)
#define BK 32   // K chunk per stage (one 16x16x32 MFMA K-step)

// LDS tile cells (16 B each, = one (kblk,m) fragment slice of 8 bf16):
//   A_hi cells [0,832)   A_lo [832,1664)   B_hi [1664,1984)   B_lo [1984,2304)
#define A_CELLS (MT * 64)          // 832 per half
#define B_CELLS (NT * 64)          // 320 per half
#define TOT_CELLS (2 * A_CELLS + 2 * B_CELLS)   // 2304 = 9 * 256

#define IMGN (BB * N1 * DD)        // 9,633,792
#define TXTN (BB * N2 * DD)        // 3,784,704

typedef short s8v __attribute__((ext_vector_type(8)));   // 8 bf16 (4 VGPR)
typedef float f4v __attribute__((ext_vector_type(4)));   // MFMA C/D

// fp32 -> bf16 round-to-nearest-even, as raw ushort
__device__ __forceinline__ unsigned short f2bf_rn(float x) {
    unsigned int u = __float_as_uint(x);
    unsigned int r = (u + 0x7fffu + ((u >> 16) & 1u)) >> 16;
    return (unsigned short)r;
}
__device__ __forceinline__ float bf2f(unsigned short h) {
    return __uint_as_float(((unsigned int)h) << 16);
}

// fp32 -> (hi, lo) bf16 split, precompute pass. 4 elements/thread.
__global__ void convert_kernel(const float* __restrict__ src,
                               unsigned short* __restrict__ hi,
                               unsigned short* __restrict__ lo, int n) {
    int i = (blockIdx.x * blockDim.x + threadIdx.x) * 4;
    if (i >= n) return;
    float4 v = *(const float4*)(src + i);
    ushort4 h, l;
    h.x = f2bf_rn(v.x); l.x = f2bf_rn(v.x - bf2f(h.x));
    h.y = f2bf_rn(v.y); l.y = f2bf_rn(v.y - bf2f(h.y));
    h.z = f2bf_rn(v.z); l.z = f2bf_rn(v.z - bf2f(h.z));
    h.w = f2bf_rn(v.w); l.w = f2bf_rn(v.w - bf2f(h.w));
    *(ushort4*)(hi + i) = h;
    *(ushort4*)(lo + i) = l;
}

// One block per (bi, bt). Computes S[208x80] = img[bi] (196x512) . txt[bt]^T
// via triple-MFMA bf16 split, then fused max/mean reductions:
//   i2t[bi,bt] = mean_q max_r S ; t2i[bt,bi] = mean_r max_q S
// PRE=true: operands pre-split into bf16 hi/lo arrays (staging = 16B moves).
// PRE=false: stage from fp32 with in-kernel split (ws too small fallback).
template <bool PRE>
__global__ __launch_bounds__(256, 2) void sim_mfma_kernel(
    const float* __restrict__ imgF, const float* __restrict__ txtF,
    const unsigned short* __restrict__ imgHi, const unsigned short* __restrict__ imgLo,
    const unsigned short* __restrict__ txtHi, const unsigned short* __restrict__ txtLo,
    float* __restrict__ i2t, float* __restrict__ t2i)
{
    const int bt = blockIdx.x, bi = blockIdx.y;
    const int tid = threadIdx.x;
    const int wave = tid >> 6, lane = tid & 63;
    const int lm = lane & 15;       // frag row/col select
    const int lq = lane >> 4;       // frag k-block select

    __shared__ __align__(16) unsigned short lds_tile[TOT_CELLS * 8];
    __shared__ float s_red[4 * 80 + 4 + 80];
    float* s_cmax = s_red;          // [wave][80]
    float* s_qsum = s_red + 320;    // [wave]
    float* s_col  = s_red + 324;    // [80]

    // ---- precompute per-thread staging descriptors (k0-invariant) ----
    const unsigned short* gp[9];    // PRE: bf16 source ptr per cell
    const float* fp[5];             // !PRE: fp32 source ptr per cell-pair
    int chi[5], clo[5];
    if (PRE) {
#pragma unroll
        for (int j = 0; j < 9; ++j) {
            int c = tid + 256 * j;  // 2304 cells = 9*256 exactly
            if (c < 2 * A_CELLS) {
                int half = (c >= A_CELLS);
                int rem = c - half * A_CELLS;
                int strip = rem >> 6, sub = rem & 63;
                int kb = sub >> 4, m = sub & 15;
                int q = strip * 16 + m; q = q > (N1 - 1) ? (N1 - 1) : q;
                const unsigned short* base = half ? imgLo : imgHi;
                gp[j] = base + ((size_t)(bi * N1 + q) * DD + kb * 8);
            } else {
                int c2 = c - 2 * A_CELLS;
                int half = (c2 >= B_CELLS);
                int rem = c2 - half * B_CELLS;
                int ct = rem >> 6, sub = rem & 63;
                int kb = sub >> 4, n = sub & 15;
                int r = ct * 16 + n; r = r > (N2 - 1) ? (N2 - 1) : r;
                const unsigned short* base = half ? txtLo : txtHi;
                gp[j] = base + ((size_t)(bt * N2 + r) * DD + kb * 8);
            }
        }
    } else {
#pragma unroll
        for (int j = 0; j < 5; ++j) {
            int p = tid + 256 * j;  // 1152 pairs; p>=1152 inactive
            if (p >= A_CELLS + B_CELLS) { fp[j] = nullptr; chi[j] = clo[j] = 0; continue; }
            if (p < A_CELLS) {
                int strip = p >> 6, sub = p & 63;
                int kb = sub >> 4, m = sub & 15;
                int q = strip * 16 + m; q = q > (N1 - 1) ? (N1 - 1) : q;
                fp[j] = imgF + ((size_t)(bi * N1 + q) * DD + kb * 8);
                chi[j] = p; clo[j] = p + A_CELLS;
            } else {
                int p2 = p - A_CELLS;
                int ct = p2 >> 6, sub = p2 & 63;
                int kb = sub >> 4, n = sub & 15;
                int r = ct * 16 + n; r = r > (N2 - 1) ? (N2 - 1) : r;
                fp[j] = txtF + ((size_t)(bt * N2 + r) * DD + kb * 8);
                chi[j] = 2 * A_CELLS + p2; clo[j] = 2 * A_CELLS + B_CELLS + p2;
            }
        }
    }

    const int nstrips = (wave == 0) ? 4 : 3;   // 13 strips round-robin over 4 waves
    f4v acc[4][NT];
#pragma unroll
    for (int i = 0; i < 4; ++i)
#pragma unroll
        for (int ct = 0; ct < NT; ++ct) acc[i][ct] = (f4v){0.f, 0.f, 0.f, 0.f};

    uint4* cells = (uint4*)lds_tile;

    // ---- K loop ----
#pragma unroll 1
    for (int k0 = 0; k0 < DD; k0 += BK) {
        __syncthreads();   // previous chunk's frag reads done before overwrite
        if (PRE) {
#pragma unroll
            for (int j = 0; j < 9; ++j) {
                uint4 v = *(const uint4*)(gp[j] + k0);
                cells[tid + 256 * j] = v;
            }
        } else {
#pragma unroll
            for (int j = 0; j < 5; ++j) {
                if (fp[j]) {
                    float4 v0 = *(const float4*)(fp[j] + k0);
                    float4 v1 = *(const float4*)(fp[j] + k0 + 4);
                    unsigned short h[8], l[8];
                    float x[8] = {v0.x, v0.y, v0.z, v0.w, v1.x, v1.y, v1.z, v1.w};
#pragma unroll
                    for (int e = 0; e < 8; ++e) {
                        h[e] = f2bf_rn(x[e]);
                        l[e] = f2bf_rn(x[e] - bf2f(h[e]));
                    }
                    uint4 hv, lv;
                    hv.x = h[0] | (h[1] << 16); hv.y = h[2] | (h[3] << 16);
                    hv.z = h[4] | (h[5] << 16); hv.w = h[6] | (h[7] << 16);
                    lv.x = l[0] | (l[1] << 16); lv.y = l[2] | (l[3] << 16);
                    lv.z = l[4] | (l[5] << 16); lv.w = l[6] | (l[7] << 16);
                    cells[chi[j]] = hv;
                    cells[clo[j]] = lv;
                }
            }
        }
        __syncthreads();

        // B fragments hoisted to registers (shared across this wave's strips)
        s8v bhi[NT], blo[NT];
#pragma unroll
        for (int ct = 0; ct < NT; ++ct) {
            bhi[ct] = ((s8v*)lds_tile)[2 * A_CELLS + ct * 64 + lq * 16 + lm];
            blo[ct] = ((s8v*)lds_tile)[2 * A_CELLS + B_CELLS + ct * 64 + lq * 16 + lm];
        }
#pragma unroll
        for (int i = 0; i < 4; ++i) {
            if (i < nstrips) {
                int s = wave + 4 * i;
                s8v ahi = ((s8v*)lds_tile)[s * 64 + lq * 16 + lm];
                s8v alo = ((s8v*)lds_tile)[A_CELLS + s * 64 + lq * 16 + lm];
#pragma unroll
                for (int ct = 0; ct < NT; ++ct) {
                    acc[i][ct] = __builtin_amdgcn_mfma_f32_16x16x32_bf16(ahi, bhi[ct], acc[i][ct], 0, 0, 0);
                    acc[i][ct] = __builtin_amdgcn_mfma_f32_16x16x32_bf16(ahi, blo[ct], acc[i][ct], 0, 0, 0);
                    acc[i][ct] = __builtin_amdgcn_mfma_f32_16x16x32_bf16(alo, bhi[ct], acc[i][ct], 0, 0, 0);
                }
            }
        }
    }

    // ---- fused reductions ----
    // C/D layout: col = lane&15, row_in_tile = (lane>>4)*4 + reg  [m89-verified]
    float qsum = 0.f;
#pragma unroll
    for (int i = 0; i < 4; ++i) {
        if (i < nstrips) {
            int s = wave + 4 * i;
#pragma unroll
            for (int reg = 0; reg < 4; ++reg) {
                float rm = fmaxf(fmaxf(acc[i][0][reg], acc[i][1][reg]),
                                 fmaxf(acc[i][2][reg], acc[i][3][reg]));
                if (lm < N2 - 64) rm = fmaxf(rm, acc[i][4][reg]);  // cols 64..76 only
                rm = fmaxf(rm, __shfl_xor(rm, 1));
                rm = fmaxf(rm, __shfl_xor(rm, 2));
                rm = fmaxf(rm, __shfl_xor(rm, 4));
                rm = fmaxf(rm, __shfl_xor(rm, 8));
                int q = s * 16 + lq * 4 + reg;
                if (lm == 0 && q < N1) qsum += rm;
            }
        }
    }
    qsum += __shfl_xor(qsum, 16);
    qsum += __shfl_xor(qsum, 32);
    if (lane == 0) s_qsum[wave] = qsum;

    float cm[NT];
#pragma unroll
    for (int ct = 0; ct < NT; ++ct) cm[ct] = -INFINITY;
#pragma unroll
    for (int i = 0; i < 4; ++i) {
        if (i < nstrips) {
            int s = wave + 4 * i;
            // strip 12 rows 196..207 invalid: only lq==0 (q=192..195) counts
            if (s < 12 || lq == 0) {
#pragma unroll
                for (int ct = 0; ct < NT; ++ct)
#pragma unroll
                    for (int reg = 0; reg < 4; ++reg)
                        cm[ct] = fmaxf(cm[ct], acc[i][ct][reg]);
            }
        }
    }
#pragma unroll
    for (int ct = 0; ct < NT; ++ct) {
        cm[ct] = fmaxf(cm[ct], __shfl_xor(cm[ct], 16));
        cm[ct] = fmaxf(cm[ct], __shfl_xor(cm[ct], 32));
    }
    if (lane < 16) {
#pragma unroll
        for (int ct = 0; ct < NT; ++ct) s_cmax[wave * 80 + ct * 16 + lane] = cm[ct];
    }
    __syncthreads();
    if (tid == 0) {
        float s = s_qsum[0] + s_qsum[1] + s_qsum[2] + s_qsum[3];
        i2t[bi * BB + bt] = s * (1.f / (float)N1);
    }
    if (tid < N2) {
        float m = fmaxf(fmaxf(s_cmax[tid], s_cmax[80 + tid]),
                        fmaxf(s_cmax[160 + tid], s_cmax[240 + tid]));
        s_col[tid] = m;
    }
    __syncthreads();
    if (tid == 0) {
        float s = 0.f;
#pragma unroll 1
        for (int r = 0; r < N2; ++r) s += s_col[r];
        t2i[bt * BB + bi] = s * (1.f / (float)N2);
    }
}

// CE with arange labels over both [B,B] logit matrices.
__global__ __launch_bounds__(256) void ce_kernel(
    const float* __restrict__ i2t, const float* __restrict__ t2i,
    float* __restrict__ out)
{
    const int tid = threadIdx.x;
    const int wid = tid >> 6;
    const int lane = tid & 63;

    float contrib = 0.f;
    if (tid < 2 * BB) {
        const float* M = (tid < BB) ? i2t : t2i;
        const int b = (tid < BB) ? tid : tid - BB;
        const float* row = M + b * BB;
        float mx = row[0];
#pragma unroll 1
        for (int c = 1; c < BB; ++c) mx = fmaxf(mx, row[c]);
        float s = 0.f;
#pragma unroll 1
        for (int c = 0; c < BB; ++c) s += expf(row[c] - mx);
        float lse = mx + logf(s);
        contrib = row[b] - lse;
    }
    contrib += __shfl_xor(contrib, 1);
    contrib += __shfl_xor(contrib, 2);
    contrib += __shfl_xor(contrib, 4);
    contrib += __shfl_xor(contrib, 8);
    contrib += __shfl_xor(contrib, 16);
    contrib += __shfl_xor(contrib, 32);

    __shared__ float s_part[4];
    if (lane == 0) s_part[wid] = contrib;
    __syncthreads();
    if (tid == 0) {
        float total = s_part[0] + s_part[1] + s_part[2] + s_part[3];
        out[0] = -total * (1.f / (float)(2 * BB));
    }
}

extern "C" void kernel_launch(void* const* d_in, const int* in_sizes, int n_in,
                              void* d_out, int out_size, void* d_ws, size_t ws_size,
                              hipStream_t stream) {
    const float* img = (const float*)d_in[0];   // [96,196,512] fp32
    const float* txt = (const float*)d_in[1];   // [96,77,512] fp32
    float* i2t = (float*)d_ws;                  // [96,96]
    float* t2i = i2t + BB * BB;                 // [96,96]

    const size_t conv_off = 2 * BB * BB * sizeof(float);   // 73728, 16B-aligned
    const size_t need = conv_off + (size_t)(IMGN + TXTN) * 2 * sizeof(unsigned short);

    dim3 grid(BB, BB);
    if (ws_size >= need) {
        unsigned short* imgHi = (unsigned short*)((char*)d_ws + conv_off);
        unsigned short* imgLo = imgHi + IMGN;
        unsigned short* txtHi = imgLo + IMGN;
        unsigned short* txtLo = txtHi + TXTN;
        convert_kernel<<<(IMGN / 4 + 255) / 256, 256, 0, stream>>>(img, imgHi, imgLo, IMGN);
        convert_kernel<<<(TXTN / 4 + 255) / 256, 256, 0, stream>>>(txt, txtHi, txtLo, TXTN);
        sim_mfma_kernel<true><<<grid, 256, 0, stream>>>(
            img, txt, imgHi, imgLo, txtHi, txtLo, i2t, t2i);
    } else {
        sim_mfma_kernel<false><<<grid, 256, 0, stream>>>(
            img, txt, nullptr, nullptr, nullptr, nullptr, i2t, t2i);
    }
    ce_kernel<<<1, 256, 0, stream>>>(i2t, t2i, (float*)d_out);
}